// Round 11
// baseline (543.960 us; speedup 1.0000x reference)
//
#include <hip/hip_runtime.h>

#define N_NODES 100000
#define E_EDGES 1600000
#define DIN 256
#define NH 4
#define DH 32
#define COUT 256
#define LN_EPS 1e-9f
#define BM 64
#define BK 32
#define KPAD (BK + 8)
#define NB 391   // ceil(N_NODES / 256)

typedef __attribute__((ext_vector_type(4))) float     f32x4;
typedef __attribute__((ext_vector_type(8))) _Float16  f16x8;
typedef __attribute__((ext_vector_type(8))) ushort    u16x8;

__device__ __forceinline__ ushort f2bf(float x) {
    union { float f; uint u; } v; v.f = x;
    uint r = v.u + 0x7fffu + ((v.u >> 16) & 1u);
    return (ushort)(r >> 16);
}

// ---------------------------------------------------------------------------
// W (2,4,256,32) f32 -> Wn[c][k] fp16 (N x K, row-major), c = o*128+h*32+q
// ---------------------------------------------------------------------------
__global__ __launch_bounds__(256) void wn_kernel(const float* __restrict__ W,
                                                 _Float16* __restrict__ Wn) {
    int i = blockIdx.x * 256 + threadIdx.x;   // 65536
    int c = i >> 8, k = i & 255;
    int o = c >> 7, h = (c >> 5) & 3, q = c & 31;
    Wn[i] = (_Float16)W[((o * NH + h) * DIN + k) * DH + q];
}

// ---------------------------------------------------------------------------
// FP16 MFMA GEMM: block = 64 rows x 256 cols, K=256 in 8 steps of 32.
// Fused epilogue: ReLU + per-head LN / att logits; feat_nei stored bf16.
// ---------------------------------------------------------------------------
__global__ __launch_bounds__(256) void gemm_kernel(
    const float* __restrict__ feat_in, const _Float16* __restrict__ Wn,
    const float* __restrict__ b, const float* __restrict__ att,
    const float* __restrict__ scale, const float* __restrict__ offset,
    float* __restrict__ out, ushort* __restrict__ feat_nei,
    float* __restrict__ att_s, float* __restrict__ att_n)
{
    __shared__ _Float16 sA[BM][KPAD];    // 5 KB
    __shared__ _Float16 sB[256][KPAD];   // 20 KB

    const int t   = threadIdx.x;
    const int wid = t >> 6;
    const int l   = t & 63;
    const int l15 = l & 15;
    const int lhi = l >> 4;
    const int m_blk = blockIdx.x * BM;

    f32x4 acc[4][4] = {};

    const int arow = t >> 2;
    const int akq  = t & 3;
    const int arow_g = min(m_blk + arow, N_NODES - 1);
    const float* aptr = feat_in + (size_t)arow_g * DIN + akq * 8;

    for (int kc = 0; kc < DIN; kc += BK) {
        float4 f0 = *(const float4*)(aptr + kc);
        float4 f1 = *(const float4*)(aptr + kc + 4);
        f16x8 ph = { (_Float16)f0.x, (_Float16)f0.y, (_Float16)f0.z,
                     (_Float16)f0.w, (_Float16)f1.x, (_Float16)f1.y,
                     (_Float16)f1.z, (_Float16)f1.w };
        *(f16x8*)&sA[arow][akq * 8] = ph;

#pragma unroll
        for (int i = 0; i < 4; ++i) {
            int c = i * 256 + t;
            int rrow = c >> 2, koff = (c & 3) * 8;
            *(f16x8*)&sB[rrow][koff] =
                *(const f16x8*)(Wn + rrow * 256 + kc + koff);
        }
        __syncthreads();

        f16x8 a[4], bb[4];
#pragma unroll
        for (int mi = 0; mi < 4; ++mi)
            a[mi] = *(f16x8*)&sA[mi * 16 + l15][lhi * 8];
#pragma unroll
        for (int ni = 0; ni < 4; ++ni)
            bb[ni] = *(f16x8*)&sB[wid * 64 + ni * 16 + l15][lhi * 8];
#pragma unroll
        for (int mi = 0; mi < 4; ++mi)
#pragma unroll
            for (int ni = 0; ni < 4; ++ni)
                acc[mi][ni] = __builtin_amdgcn_mfma_f32_16x16x32_f16(
                    a[mi], bb[ni], acc[mi][ni], 0, 0, 0);
        __syncthreads();
    }

    // ---- epilogue ----
    const int o = wid >> 1;
    float bias[4], attw[4], sc[4], of[4];
#pragma unroll
    for (int ni = 0; ni < 4; ++ni) {
        int c = wid * 64 + ni * 16 + l15;
        int h = (c >> 5) & 3;
        bias[ni] = b[c];
        sc[ni]   = scale[c];
        of[ni]   = offset[c];
        attw[ni] = att[h * 64 + o * 32 + (c & 31)];
    }

#pragma unroll
    for (int mi = 0; mi < 4; ++mi) {
#pragma unroll
        for (int r = 0; r < 4; ++r) {
            int row = m_blk + mi * 16 + lhi * 4 + r;
            float v[4];
#pragma unroll
            for (int ni = 0; ni < 4; ++ni)
                v[ni] = fmaxf(acc[mi][ni][r] + bias[ni], 0.f);
#pragma unroll
            for (int p = 0; p < 2; ++p) {
                float x0 = v[2 * p], x1 = v[2 * p + 1];
                float s1 = x0 + x1;
                float s2 = x0 * x0 + x1 * x1;
                float sa = x0 * attw[2 * p] + x1 * attw[2 * p + 1];
#pragma unroll
                for (int off = 1; off < 16; off <<= 1) {
                    s1 += __shfl_xor(s1, off);
                    s2 += __shfl_xor(s2, off);
                    sa += __shfl_xor(sa, off);
                }
                float mean = s1 * (1.f / 32.f);
                float var  = s2 * (1.f / 32.f) - mean * mean;
                float rstd = rsqrtf(fmaxf(var, 0.f) + LN_EPS);
                float a_out = sa >= 0.f ? sa : 0.2f * sa;
                if (row < N_NODES) {
                    int hloc = (wid & 1) * 2 + p;
                    if (o == 0) {
#pragma unroll
                        for (int q = 0; q < 2; ++q) {
                            int ni = 2 * p + q;
                            int c = wid * 64 + ni * 16 + l15;
                            out[(size_t)row * COUT + c] =
                                (v[ni] - mean) * rstd * sc[ni] + of[ni];
                        }
                        if (l15 == 0) att_s[hloc * N_NODES + row] = a_out;
                    } else {
#pragma unroll
                        for (int q = 0; q < 2; ++q) {
                            int ni = 2 * p + q;
                            int c = wid * 64 + ni * 16 + l15 - 128;
                            feat_nei[(size_t)row * 128 + c] = f2bf(v[ni]);
                        }
                        if (l15 == 0) att_n[hloc * N_NODES + row] = a_out;
                    }
                }
            }
        }
    }
}

// ---------------------------------------------------------------------------
// CSR build step 1: histogram of rows.
// ---------------------------------------------------------------------------
__global__ __launch_bounds__(256) void hist_kernel(const int* __restrict__ row,
                                                   int* __restrict__ cnt) {
    int e = blockIdx.x * 256 + threadIdx.x;
    atomicAdd(&cnt[row[e]], 1);
}

// ---------------------------------------------------------------------------
// Hierarchical scan (3 kernels): per-block sums -> scan sums -> final.
// ---------------------------------------------------------------------------
__global__ __launch_bounds__(256) void scan1_kernel(const int* __restrict__ cnt,
                                                    int* __restrict__ bsum) {
    int i = blockIdx.x * 256 + threadIdx.x;
    int v = (i < N_NODES) ? cnt[i] : 0;
#pragma unroll
    for (int off = 1; off < 64; off <<= 1) v += __shfl_xor(v, off);
    __shared__ int s[4];
    if ((threadIdx.x & 63) == 0) s[threadIdx.x >> 6] = v;
    __syncthreads();
    if (threadIdx.x == 0) bsum[blockIdx.x] = s[0] + s[1] + s[2] + s[3];
}

__global__ __launch_bounds__(512) void scan2_kernel(const int* __restrict__ bsum,
                                                    int* __restrict__ boff) {
    __shared__ int s[512];
    int t = threadIdx.x;
    int v = (t < NB) ? bsum[t] : 0;
    s[t] = v;
    __syncthreads();
#pragma unroll
    for (int off = 1; off < 512; off <<= 1) {
        int u = (t >= off) ? s[t - off] : 0;
        __syncthreads();
        s[t] += u;
        __syncthreads();
    }
    if (t < NB) boff[t] = s[t] - v;   // exclusive prefix
}

__global__ __launch_bounds__(256) void scan3_kernel(const int* __restrict__ cnt,
                                                    const int* __restrict__ boff,
                                                    int* __restrict__ start,
                                                    int* __restrict__ pos) {
    __shared__ int s[256];
    int t = threadIdx.x;
    int i = blockIdx.x * 256 + t;
    int v = (i < N_NODES) ? cnt[i] : 0;
    s[t] = v;
    __syncthreads();
#pragma unroll
    for (int off = 1; off < 256; off <<= 1) {
        int u = (t >= off) ? s[t - off] : 0;
        __syncthreads();
        s[t] += u;
        __syncthreads();
    }
    if (i < N_NODES) {
        int e = boff[blockIdx.x] + s[t] - v;   // global exclusive prefix
        start[i] = e;
        pos[i]   = e;
    }
}

// ---------------------------------------------------------------------------
// CSR build step 3: scatter edges packed as 4B: col<<15 | f16bits(adj).
// adj in [0,1) -> fp16 sign bit is 0, so 15 bits hold the full fp16 value.
// ---------------------------------------------------------------------------
__global__ __launch_bounds__(256) void scatter_kernel(
    const int* __restrict__ row, const int* __restrict__ col,
    const float* __restrict__ adj, int* __restrict__ pos,
    uint* __restrict__ eca) {
    int e = blockIdx.x * 256 + threadIdx.x;
    int r = row[e];
    union { _Float16 h; ushort u; } cv;
    cv.h = (_Float16)adj[e];
    uint pk = ((uint)col[e] << 15) | (uint)(cv.u & 0x7fffu);
    int slot = atomicAdd(&pos[r], 1);
    eca[slot] = pk;
}

// ---------------------------------------------------------------------------
// Gather: one wave per node; lane l -> channels 2l,2l+1 (h = l>>4);
// eca packed 4B; feat_nei bf16; 2-edge pipeline; fused LN.
// ---------------------------------------------------------------------------
__global__ __launch_bounds__(256) void gather_kernel(
    const int* __restrict__ start, const int* __restrict__ cnt,
    const uint* __restrict__ eca,
    const float* __restrict__ att_s, const float* __restrict__ att_n,
    const ushort* __restrict__ feat_nei,
    const float* __restrict__ scale, const float* __restrict__ offset,
    float* __restrict__ out)
{
    int w = threadIdx.x >> 6;
    int l = threadIdx.x & 63;
    int n = blockIdx.x * 4 + w;
    if (n >= N_NODES) return;
    int h  = l >> 4;
    int c2 = l * 2;
    float a_s = att_s[h * N_NODES + n];
    const float* attn_h = att_n + h * N_NODES;
    int s0 = start[n], d = cnt[n];
    float ax = 0.f, ay = 0.f;

    int i = 0;
    for (; i + 2 <= d; i += 2) {
        uint pk0 = eca[s0 + i];
        uint pk1 = eca[s0 + i + 1];
        int c0 = pk0 >> 15;
        int c1 = pk1 >> 15;
        uint f0 = *(const uint*)&feat_nei[(size_t)c0 * 128 + c2];
        uint f1 = *(const uint*)&feat_nei[(size_t)c1 * 128 + c2];
        union { ushort u; _Float16 hf; } a0, a1;
        a0.u = (ushort)(pk0 & 0x7fffu);
        a1.u = (ushort)(pk1 & 0x7fffu);
        float w0 = (a_s + attn_h[c0]) * (float)a0.hf;
        float w1 = (a_s + attn_h[c1]) * (float)a1.hf;
        union { uint u; float f; } lo0, hi0, lo1, hi1;
        lo0.u = f0 << 16;         hi0.u = f0 & 0xffff0000u;
        lo1.u = f1 << 16;         hi1.u = f1 & 0xffff0000u;
        ax = fmaf(w0, lo0.f, ax); ay = fmaf(w0, hi0.f, ay);
        ax = fmaf(w1, lo1.f, ax); ay = fmaf(w1, hi1.f, ay);
    }
    if (i < d) {
        uint pk0 = eca[s0 + i];
        int c0 = pk0 >> 15;
        uint f0 = *(const uint*)&feat_nei[(size_t)c0 * 128 + c2];
        union { ushort u; _Float16 hf; } a0;
        a0.u = (ushort)(pk0 & 0x7fffu);
        float w0 = (a_s + attn_h[c0]) * (float)a0.hf;
        union { uint u; float f; } lo0, hi0;
        lo0.u = f0 << 16;         hi0.u = f0 & 0xffff0000u;
        ax = fmaf(w0, lo0.f, ax); ay = fmaf(w0, hi0.f, ay);
    }

    float s1 = ax + ay, s2 = ax * ax + ay * ay;
#pragma unroll
    for (int off = 1; off < 16; off <<= 1) {
        s1 += __shfl_xor(s1, off);
        s2 += __shfl_xor(s2, off);
    }
    float mean = s1 * (1.f / 32.f);
    float var  = s2 * (1.f / 32.f) - mean * mean;
    float rstd = rsqrtf(fmaxf(var, 0.f) + LN_EPS);
    int ci = 128 + c2;
    float2 o2;
    o2.x = (ax - mean) * rstd * scale[ci]     + offset[ci];
    o2.y = (ay - mean) * rstd * scale[ci + 1] + offset[ci + 1];
    *(float2*)&out[n * COUT + ci] = o2;
}

// ---------------------------------------------------------------------------
extern "C" void kernel_launch(void* const* d_in, const int* in_sizes, int n_in,
                              void* d_out, int out_size, void* d_ws, size_t ws_size,
                              hipStream_t stream)
{
    const float* feat_in = (const float*)d_in[0];
    const int*   row     = (const int*)d_in[1];
    const int*   col     = (const int*)d_in[2];
    const float* adj     = (const float*)d_in[3];
    const float* W       = (const float*)d_in[4];
    const float* b       = (const float*)d_in[5];
    const float* att     = (const float*)d_in[6];
    const float* scale   = (const float*)d_in[7];
    const float* offset  = (const float*)d_in[8];
    float* out = (float*)d_out;

    float*     ws       = (float*)d_ws;
    _Float16*  Wn       = (_Float16*)ws;             // 65536 fp16 = 32768 f32
    float*     att_s    = ws + 32768;
    float*     att_n    = att_s + NH * N_NODES;
    ushort*    feat_b   = (ushort*)(att_n + NH * N_NODES);  // N*128 bf16
    int*       cnt      = (int*)(feat_b + (size_t)N_NODES * 128);
    int*       startp   = cnt + N_NODES;
    int*       pos      = startp + N_NODES;
    int*       bsum     = pos + N_NODES;             // 392
    int*       boff     = bsum + 392;                // 392
    uint*      eca      = (uint*)(boff + 392);       // E uint (6.4 MB)

    hipMemsetAsync(cnt, 0, N_NODES * sizeof(int), stream);
    wn_kernel<<<256, 256, 0, stream>>>(W, Wn);
    gemm_kernel<<<(N_NODES + BM - 1) / BM, 256, 0, stream>>>(
        feat_in, Wn, b, att, scale, offset, out, feat_b, att_s, att_n);
    hist_kernel<<<E_EDGES / 256, 256, 0, stream>>>(row, cnt);
    scan1_kernel<<<NB, 256, 0, stream>>>(cnt, bsum);
    scan2_kernel<<<1, 512, 0, stream>>>(bsum, boff);
    scan3_kernel<<<NB, 256, 0, stream>>>(cnt, boff, startp, pos);
    scatter_kernel<<<E_EDGES / 256, 256, 0, stream>>>(row, col, adj, pos, eca);
    gather_kernel<<<(N_NODES + 3) / 4, 256, 0, stream>>>(startp, cnt, eca, att_s,
                                                         att_n, feat_b, scale,
                                                         offset, out);
}